// Round 3
// baseline (4760.465 us; speedup 1.0000x reference)
//
#include <hip/hip_runtime.h>
#include <math.h>

typedef unsigned short u16;
typedef unsigned int u32;
typedef __attribute__((ext_vector_type(8))) short bf16x8;
typedef __attribute__((ext_vector_type(4))) float f32x4;

#define SCALE_ATTN 0.125f  // D_K=64 -> 1/sqrt(64)

__device__ __forceinline__ float bf2f(u16 u) {
    union { u32 i; float f; } x; x.i = ((u32)u) << 16; return x.f;
}
__device__ __forceinline__ u16 f2bf(float f) {
    union { float f; u32 i; } x; x.f = f;
    u32 i = x.i;
    return (u16)((i + 0x7FFFu + ((i >> 16) & 1u)) >> 16);
}

// ---------------------------------------------------------------------------
// Tiled MFMA GEMM: C[M,N] = act(A[M,K] @ B[N,K]^T + bias) (+resid)
// B (weights) and bias are f32 in global; converted to bf16 at staging.
// AMODE: 0 = A is f32, 1 = A is bf16
// ACT:   0 = none, 1 = exact GELU
// OBF:   0 = f32 out, 1 = bf16 out
// RES:   0 = none, 1 = f32 residual
// CHAN:  1 = add chan[row/128][k] (f32) to A rows during staging (K==512)
// ---------------------------------------------------------------------------
template<int AMODE, int ACT, int OBF, int RES, int CHAN>
__global__ __launch_bounds__(256) void gemm_kernel(
    const void* __restrict__ Av, const float* __restrict__ B,
    const float* __restrict__ bias, const float* __restrict__ resv,
    const float* __restrict__ chan, void* __restrict__ Ov,
    int M, int N, int K)
{
    __shared__ u16 As[64][40];
    __shared__ u16 Bs[64][40];
    const int tid = threadIdx.x;
    const int m0 = blockIdx.x * 64, n0 = blockIdx.y * 64;
    const int lane = tid & 63, wave = tid >> 6;
    const int wm = wave >> 1, wn = wave & 1;
    const int srow = tid >> 2;        // 0..63
    const int scol = (tid & 3) * 8;   // 0,8,16,24

    f32x4 acc[2][2] = {};

    for (int k0 = 0; k0 < K; k0 += 32) {
        // stage B (f32 weight [N,K] -> bf16)
        {
            const float* p = &B[(size_t)(n0 + srow) * K + k0 + scol];
            float4 v0 = *(const float4*)p;
            float4 v1 = *(const float4*)(p + 4);
            float bv[8] = {v0.x, v0.y, v0.z, v0.w, v1.x, v1.y, v1.z, v1.w};
            bf16x8 pk;
            #pragma unroll
            for (int j = 0; j < 8; ++j) pk[j] = (short)f2bf(bv[j]);
            *(bf16x8*)&Bs[srow][scol] = pk;
        }
        // stage A
        if (AMODE == 1) {
            const u16* Ab = (const u16*)Av;
            bf16x8 av = *(const bf16x8*)&Ab[(size_t)(m0 + srow) * K + k0 + scol];
            if (CHAN) {
                const float* cp = &chan[(size_t)((m0 + srow) >> 7) * 512 + k0 + scol];
                bf16x8 pk;
                #pragma unroll
                for (int j = 0; j < 8; ++j)
                    pk[j] = (short)f2bf(bf2f((u16)av[j]) + cp[j]);
                *(bf16x8*)&As[srow][scol] = pk;
            } else {
                *(bf16x8*)&As[srow][scol] = av;
            }
        } else {
            const float* Af = (const float*)Av;
            const float* p = &Af[(size_t)(m0 + srow) * K + k0 + scol];
            float4 v0 = *(const float4*)p;
            float4 v1 = *(const float4*)(p + 4);
            float av[8] = {v0.x, v0.y, v0.z, v0.w, v1.x, v1.y, v1.z, v1.w};
            if (CHAN) {
                const float* cp = &chan[(size_t)((m0 + srow) >> 7) * 512 + k0 + scol];
                #pragma unroll
                for (int j = 0; j < 8; ++j) av[j] += cp[j];
            }
            bf16x8 pk;
            #pragma unroll
            for (int j = 0; j < 8; ++j) pk[j] = (short)f2bf(av[j]);
            *(bf16x8*)&As[srow][scol] = pk;
        }
        __syncthreads();
        bf16x8 af[2], bfv[2];
        #pragma unroll
        for (int mi = 0; mi < 2; ++mi)
            af[mi] = *(const bf16x8*)&As[wm * 32 + mi * 16 + (lane & 15)][(lane >> 4) * 8];
        #pragma unroll
        for (int ni = 0; ni < 2; ++ni)
            bfv[ni] = *(const bf16x8*)&Bs[wn * 32 + ni * 16 + (lane & 15)][(lane >> 4) * 8];
        #pragma unroll
        for (int mi = 0; mi < 2; ++mi)
            #pragma unroll
            for (int ni = 0; ni < 2; ++ni)
                acc[mi][ni] = __builtin_amdgcn_mfma_f32_16x16x32_bf16(
                    af[mi], bfv[ni], acc[mi][ni], 0, 0, 0);
        __syncthreads();
    }

    #pragma unroll
    for (int mi = 0; mi < 2; ++mi)
    #pragma unroll
    for (int ni = 0; ni < 2; ++ni)
    #pragma unroll
    for (int r = 0; r < 4; ++r) {
        int row = m0 + wm * 32 + mi * 16 + (lane >> 4) * 4 + r;
        int col = n0 + wn * 32 + ni * 16 + (lane & 15);
        float v = acc[mi][ni][r] + bias[col];
        if (RES == 1) v += resv[(size_t)row * N + col];
        if (ACT == 1) v = 0.5f * v * (1.0f + erff(v * 0.70710678118f));
        if (OBF) ((u16*)Ov)[(size_t)row * N + col] = f2bf(v);
        else     ((float*)Ov)[(size_t)row * N + col] = v;
    }
}

// ---------------------------------------------------------------------------
// Temporal attention: one block per (b, h); thread t owns query row t.
// Q,K,V bf16 [B*128, 512] head-interleaved; writes out_tf (bf16) to merged.
// ---------------------------------------------------------------------------
__global__ __launch_bounds__(128) void attn_kernel(
    const u16* __restrict__ Q, const u16* __restrict__ K,
    const u16* __restrict__ V, u16* __restrict__ merged)
{
    __shared__ float Ks[128][64];
    __shared__ float Vs[128][64];
    const int b = blockIdx.x, h = blockIdx.y;
    const int tid = threadIdx.x;
    const size_t base = ((size_t)b * 128) * 512 + (size_t)h * 64;

    for (int i = tid; i < 1024; i += 128) {
        int r = i >> 3, c8 = (i & 7) * 8;
        bf16x8 kv = *(const bf16x8*)&K[base + (size_t)r * 512 + c8];
        bf16x8 vv = *(const bf16x8*)&V[base + (size_t)r * 512 + c8];
        #pragma unroll
        for (int j = 0; j < 8; ++j) {
            Ks[r][c8 + j] = bf2f((u16)kv[j]);
            Vs[r][c8 + j] = bf2f((u16)vv[j]);
        }
    }
    __syncthreads();

    float q[64];
    {
        const u16* qp = &Q[base + (size_t)tid * 512];
        #pragma unroll
        for (int d = 0; d < 64; d += 8) {
            bf16x8 t = *(const bf16x8*)&qp[d];
            #pragma unroll
            for (int j = 0; j < 8; ++j) q[d + j] = bf2f((u16)t[j]);
        }
    }
    float m = -1e30f, l = 0.f;
    float o[64];
    #pragma unroll
    for (int d = 0; d < 64; ++d) o[d] = 0.f;

    for (int j = 0; j < 128; ++j) {
        float s0 = 0.f, s1 = 0.f, s2 = 0.f, s3 = 0.f;
        #pragma unroll
        for (int d = 0; d < 64; d += 4) {
            s0 += q[d]     * Ks[j][d];
            s1 += q[d + 1] * Ks[j][d + 1];
            s2 += q[d + 2] * Ks[j][d + 2];
            s3 += q[d + 3] * Ks[j][d + 3];
        }
        float s = ((s0 + s1) + (s2 + s3)) * SCALE_ATTN;
        float mn = fmaxf(m, s);
        float al = __expf(m - mn);
        float p  = __expf(s - mn);
        l = l * al + p;
        #pragma unroll
        for (int d = 0; d < 64; ++d) o[d] = o[d] * al + p * Vs[j][d];
        m = mn;
    }
    float inv = 1.f / l;
    u16* op = &merged[base + (size_t)tid * 512];
    #pragma unroll
    for (int d = 0; d < 64; d += 8) {
        bf16x8 pk;
        #pragma unroll
        for (int j = 0; j < 8; ++j) pk[j] = (short)f2bf(o[d + j] * inv);
        *(bf16x8*)&op[d] = pk;
    }
}

// ---------------------------------------------------------------------------
// Channel-compression attention. One block per (bs, h); wave = query row
// (D_COMP=8). Keys indexed j = c*128 + t, values indexed j = t*32 + c
// (replicating the reference's mismatched flatten orders).
// oc layout: [bs][q][h*64+d] (f32). router is f32 input.
// ---------------------------------------------------------------------------
__global__ __launch_bounds__(512) void chan_oc_kernel(
    const u16* __restrict__ K, const u16* __restrict__ V,
    const float* __restrict__ router, float* __restrict__ oc)
{
    const int bs = blockIdx.x, h = blockIdx.y;
    const int qrow = threadIdx.x >> 6;
    const int lane = threadIdx.x & 63;

    float rq[64];
    {
        const float* rp = &router[(size_t)(h * 8 + qrow) * 64];
        #pragma unroll
        for (int d = 0; d < 64; d += 4) {
            float4 t = *(const float4*)&rp[d];
            rq[d] = t.x; rq[d + 1] = t.y; rq[d + 2] = t.z; rq[d + 3] = t.w;
        }
    }
    float m = -1e30f, l = 0.f;
    float o[64];
    #pragma unroll
    for (int d = 0; d < 64; ++d) o[d] = 0.f;

    for (int it = 0; it < 64; ++it) {
        int j = it * 64 + lane;          // 0..4095
        int kc = j >> 7, kt = j & 127;   // key decode: j = c*128 + t
        const u16* kp = &K[((size_t)((bs * 32 + kc) * 128 + kt)) * 512 + h * 64];
        float s0 = 0.f, s1 = 0.f, s2 = 0.f, s3 = 0.f;
        #pragma unroll
        for (int d = 0; d < 64; d += 8) {
            bf16x8 t = *(const bf16x8*)&kp[d];
            s0 += rq[d + 0] * bf2f((u16)t[0]);
            s1 += rq[d + 1] * bf2f((u16)t[1]);
            s2 += rq[d + 2] * bf2f((u16)t[2]);
            s3 += rq[d + 3] * bf2f((u16)t[3]);
            s0 += rq[d + 4] * bf2f((u16)t[4]);
            s1 += rq[d + 5] * bf2f((u16)t[5]);
            s2 += rq[d + 6] * bf2f((u16)t[6]);
            s3 += rq[d + 7] * bf2f((u16)t[7]);
        }
        float s = ((s0 + s1) + (s2 + s3)) * SCALE_ATTN;
        int vcc = j & 31, vt = j >> 5;   // value decode: j = t*32 + c
        const u16* vp = &V[((size_t)((bs * 32 + vcc) * 128 + vt)) * 512 + h * 64];
        float mn = fmaxf(m, s);
        float al = __expf(m - mn);
        float p  = __expf(s - mn);
        l = l * al + p;
        #pragma unroll
        for (int d = 0; d < 64; d += 8) {
            bf16x8 t = *(const bf16x8*)&vp[d];
            #pragma unroll
            for (int jj = 0; jj < 8; ++jj)
                o[d + jj] = o[d + jj] * al + p * bf2f((u16)t[jj]);
        }
        m = mn;
    }
    // merge partial softmax states across the 64 lanes
    #pragma unroll
    for (int off = 1; off < 64; off <<= 1) {
        float m2 = __shfl_xor(m, off);
        float l2 = __shfl_xor(l, off);
        float mn = fmaxf(m, m2);
        float a1 = __expf(m - mn), a2 = __expf(m2 - mn);
        l = l * a1 + l2 * a2;
        #pragma unroll
        for (int d = 0; d < 64; ++d) {
            float o2 = __shfl_xor(o[d], off);
            o[d] = o[d] * a1 + o2 * a2;
        }
        m = mn;
    }
    if (lane == 0) {
        float inv = 1.f / l;
        float* op = &oc[((size_t)bs * 8 + qrow) * 512 + h * 64];
        #pragma unroll
        for (int d = 0; d < 64; ++d) op[d] = o[d] * inv;
    }
}

// chan[b][d] = sum_q m_expand[c][q] * (oc[bs][q][d] + pos[q][d]), b = bs*32+c
__global__ __launch_bounds__(512) void chan_combine_kernel(
    const float* __restrict__ oc, const float* __restrict__ pos,
    const float* __restrict__ mexp, float* __restrict__ chan)
{
    const int b = blockIdx.x;           // 0..1023
    const int bs = b >> 5, c = b & 31;
    const int d = threadIdx.x;          // 0..511
    float acc = 0.f;
    #pragma unroll
    for (int q = 0; q < 8; ++q)
        acc += mexp[c * 8 + q] *
               (oc[((size_t)bs * 8 + q) * 512 + d] + pos[q * 512 + d]);
    chan[(size_t)b * 512 + d] = acc;
}

// LayerNorm over last dim (512). One wave per row, 4 rows per block.
__global__ __launch_bounds__(256) void ln_kernel(
    const float* __restrict__ in, const float* __restrict__ g,
    const float* __restrict__ bb, float* __restrict__ out)
{
    const size_t row = (size_t)blockIdx.x * 4 + (threadIdx.x >> 6);
    const int t = threadIdx.x & 63;
    const float* p = in + row * 512;
    float4 v0 = *(const float4*)(p + t * 4);
    float4 v1 = *(const float4*)(p + 256 + t * 4);
    float s = (v0.x + v0.y) + (v0.z + v0.w) + (v1.x + v1.y) + (v1.z + v1.w);
    #pragma unroll
    for (int off = 1; off < 64; off <<= 1) s += __shfl_xor(s, off);
    const float mean = s * (1.0f / 512.0f);
    float a, ss = 0.f;
    a = v0.x - mean; ss += a * a;  a = v0.y - mean; ss += a * a;
    a = v0.z - mean; ss += a * a;  a = v0.w - mean; ss += a * a;
    a = v1.x - mean; ss += a * a;  a = v1.y - mean; ss += a * a;
    a = v1.z - mean; ss += a * a;  a = v1.w - mean; ss += a * a;
    #pragma unroll
    for (int off = 1; off < 64; off <<= 1) ss += __shfl_xor(ss, off);
    const float rstd = rsqrtf(ss * (1.0f / 512.0f) + 1e-5f);
    const int c0 = t * 4, c1 = 256 + t * 4;
    float4 g0 = *(const float4*)(g + c0), g1v = *(const float4*)(g + c1);
    float4 b0 = *(const float4*)(bb + c0), b1v = *(const float4*)(bb + c1);
    float4 r0, r1;
    r0.x = (v0.x - mean) * rstd * g0.x + b0.x;
    r0.y = (v0.y - mean) * rstd * g0.y + b0.y;
    r0.z = (v0.z - mean) * rstd * g0.z + b0.z;
    r0.w = (v0.w - mean) * rstd * g0.w + b0.w;
    r1.x = (v1.x - mean) * rstd * g1v.x + b1v.x;
    r1.y = (v1.y - mean) * rstd * g1v.y + b1v.y;
    r1.z = (v1.z - mean) * rstd * g1v.z + b1v.z;
    r1.w = (v1.w - mean) * rstd * g1v.w + b1v.w;
    float* of = out + row * 512;
    *(float4*)(of + c0) = r0;
    *(float4*)(of + c1) = r1;
}

// ---------------------------------------------------------------------------
extern "C" void kernel_launch(void* const* d_in, const int* in_sizes, int n_in,
                              void* d_out, int out_size, void* d_ws, size_t ws_size,
                              hipStream_t stream)
{
    const float* src    = (const float*)d_in[0];
    const float* Wq     = (const float*)d_in[1];
    const float* bq     = (const float*)d_in[2];
    const float* Wk     = (const float*)d_in[3];
    const float* bk     = (const float*)d_in[4];
    const float* Wv     = (const float*)d_in[5];
    const float* bv     = (const float*)d_in[6];
    const float* Wo     = (const float*)d_in[7];
    const float* bo     = (const float*)d_in[8];
    const float* router = (const float*)d_in[9];
    const float* mexp   = (const float*)d_in[10];
    const float* pos    = (const float*)d_in[11];
    const float* g1     = (const float*)d_in[12];
    const float* b1     = (const float*)d_in[13];
    const float* Wf1    = (const float*)d_in[14];
    const float* bf1    = (const float*)d_in[15];
    const float* Wf2    = (const float*)d_in[16];
    const float* bf2_   = (const float*)d_in[17];
    const float* g2     = (const float*)d_in[18];
    const float* b2     = (const float*)d_in[19];

    float* out = (float*)d_out;   // also used as h1/h2 scratch (268 MB)

    char* ws = (char*)d_ws;
    // ws layout (bytes). Peak use: 539,492,352 (~515 MB).
    u16*   Qb     = (u16*)(ws + 0);              // 134217728  bf16 Q
    u16*   Kb     = (u16*)(ws + 134217728);      // 134217728  bf16 K
    u16*   Vb     = (u16*)(ws + 268435456);      // 134217728  bf16 V
    u16*   merged = (u16*)(ws + 402653184);      // 134217728  bf16 out_tf
    float* oc     = (float*)(ws + 536870912);    // 524288 = 32*8*512*4 B
    float* chan   = (float*)(ws + 537395200);    // 2097152 (FIX: was overlapping oc)
    // overlays (live only after the attention+chan phase is done):
    float* x      = (float*)(ws + 0);            // 268435456  f32 LN1 out (over Q,K)
    u16*   gbuf   = (u16*)(ws + 268435456);      // 134217728  bf16 gelu chunk (over V,merged)

    const dim3 blk(256);
    // QKV projections (src f32 -> bf16 out, head-interleaved col order)
    gemm_kernel<0, 0, 1, 0, 0><<<dim3(2048, 8), blk, 0, stream>>>(
        src, Wq, bq, nullptr, nullptr, Qb, 131072, 512, 512);
    gemm_kernel<0, 0, 1, 0, 0><<<dim3(2048, 8), blk, 0, stream>>>(
        src, Wk, bk, nullptr, nullptr, Kb, 131072, 512, 512);
    gemm_kernel<0, 0, 1, 0, 0><<<dim3(2048, 8), blk, 0, stream>>>(
        src, Wv, bv, nullptr, nullptr, Vb, 131072, 512, 512);
    // temporal attention -> merged (bf16)
    attn_kernel<<<dim3(1024, 8), dim3(128), 0, stream>>>(Qb, Kb, Vb, merged);
    // channel compression path
    chan_oc_kernel<<<dim3(32, 8), dim3(512), 0, stream>>>(Kb, Vb, router, oc);
    chan_combine_kernel<<<dim3(1024), dim3(512), 0, stream>>>(oc, pos, mexp, chan);
    // h1 = src + (merged + chan) @ Wo^T + bo   -> d_out (f32)
    gemm_kernel<1, 0, 0, 1, 1><<<dim3(2048, 8), blk, 0, stream>>>(
        merged, Wo, bo, src, chan, out, 131072, 512, 512);
    // x = LN1(h1)
    ln_kernel<<<dim3(32768), blk, 0, stream>>>(out, g1, b1, x);
    // FF in 4 M-chunks of 32768 rows (gelu buffer reuse keeps ws small)
    for (int c = 0; c < 4; ++c) {
        const size_t off = (size_t)c * 32768 * 512;
        // g = gelu(x @ Wf1^T + bf1)  (bf16)
        gemm_kernel<0, 1, 1, 0, 0><<<dim3(512, 32), blk, 0, stream>>>(
            x + off, Wf1, bf1, nullptr, nullptr, gbuf, 32768, 2048, 512);
        // h2 = x + g @ Wf2^T + bf2  -> d_out rows (f32)
        gemm_kernel<1, 0, 0, 1, 0><<<dim3(512, 8), blk, 0, stream>>>(
            gbuf, Wf2, bf2_, x + off, nullptr, out + off, 32768, 512, 2048);
    }
    // out = LN2(h2), in place on d_out
    ln_kernel<<<dim3(32768), blk, 0, stream>>>(out, g2, b2, out);
}

// Round 4
// 2492.376 us; speedup vs baseline: 1.9100x; 1.9100x over previous
//
#include <hip/hip_runtime.h>
#include <math.h>

typedef unsigned short u16;
typedef unsigned int u32;
typedef __attribute__((ext_vector_type(8))) short bf16x8;
typedef __attribute__((ext_vector_type(4))) float f32x4;

__device__ __forceinline__ float bf2f(u16 u) {
    union { u32 i; float f; } x; x.i = ((u32)u) << 16; return x.f;
}
__device__ __forceinline__ u16 f2bf(float f) {
    union { float f; u32 i; } x; x.f = f;
    u32 i = x.i;
    return (u16)((i + 0x7FFFu + ((i >> 16) & 1u)) >> 16);
}
__device__ __forceinline__ void async_copy16(void* lds, const void* g) {
    __builtin_amdgcn_global_load_lds(
        (const __attribute__((address_space(1))) void*)g,
        (__attribute__((address_space(3))) void*)lds, 16, 0, 0);
}

// f32 -> bf16 bulk convert; n must be divisible by 1024; grid = n/1024
__global__ __launch_bounds__(256) void conv_kernel(
    const float* __restrict__ in, u16* __restrict__ out)
{
    const int i = (blockIdx.x * 256 + threadIdx.x) * 4;
    float4 v = *(const float4*)&in[i];
    u32 lo = (u32)f2bf(v.x) | ((u32)f2bf(v.y) << 16);
    u32 hi = (u32)f2bf(v.z) | ((u32)f2bf(v.w) << 16);
    *(uint2*)&out[i] = make_uint2(lo, hi);
}

// ---------------------------------------------------------------------------
// 128x128-tile MFMA GEMM (m97 structure): C[M,N] = act(A @ B^T + bias)(+res)
// B is bf16 [N,K] (pre-converted weights) staged via global_load_lds.
// AMODE: 0 = A f32 (reg-stage + convert), 1 = A bf16 (global_load_lds)
// ACT: 1 = exact GELU. OBF: 1 = bf16 out. RES: 0 none, 1 f32, 2 bf16.
// ---------------------------------------------------------------------------
template<int AMODE, int ACT, int OBF, int RES>
__global__ __launch_bounds__(256) void gemm_kernel(
    const void* __restrict__ Av, const u16* __restrict__ B,
    const float* __restrict__ bias, const void* __restrict__ resv,
    void* __restrict__ Ov, int M, int N, int K)
{
    __shared__ u16 As[128 * 64];
    __shared__ u16 Bs[128 * 64];
    const int tid = threadIdx.x;
    const int m0 = blockIdx.x * 128, n0 = blockIdx.y * 128;
    const int lane = tid & 63;
    const int wm = (tid >> 7), wn = (tid >> 6) & 1;     // 2x2 waves
    const int li = lane & 15, g = lane >> 4;

    f32x4 acc[4][4] = {};

    for (int k0 = 0; k0 < K; k0 += 64) {
        // ---- stage B tile [128 x 64] bf16 via global_load_lds (16B) ----
        {
            const int wbase = tid & 192;                 // wave*64
            #pragma unroll
            for (int i = 0; i < 4; ++i) {
                const int c = i * 256 + tid;             // chunk 0..1023
                const int row = c >> 3, cc = c & 7;
                const u16* gp = &B[(size_t)(n0 + row) * K + k0 + cc * 8];
                async_copy16(&Bs[(size_t)(i * 256 + wbase) * 8], gp);
            }
        }
        // ---- stage A tile ----
        if (AMODE == 1) {
            const u16* Ab = (const u16*)Av;
            const int wbase = tid & 192;
            #pragma unroll
            for (int i = 0; i < 4; ++i) {
                const int c = i * 256 + tid;
                const int row = c >> 3, cc = c & 7;
                const u16* gp = &Ab[(size_t)(m0 + row) * K + k0 + cc * 8];
                async_copy16(&As[(size_t)(i * 256 + wbase) * 8], gp);
            }
        } else {
            const float* Af = (const float*)Av;
            #pragma unroll
            for (int i = 0; i < 8; ++i) {
                const int c = i * 256 + tid;             // f32-quad 0..2047
                const int row = c >> 4, qc = c & 15;
                float4 v = *(const float4*)&Af[(size_t)(m0 + row) * K + k0 + qc * 4];
                u32 lo = (u32)f2bf(v.x) | ((u32)f2bf(v.y) << 16);
                u32 hi = (u32)f2bf(v.z) | ((u32)f2bf(v.w) << 16);
                *(uint2*)&As[row * 64 + qc * 4] = make_uint2(lo, hi);
            }
        }
        __syncthreads();
        // ---- compute: 2 k-steps of 32, 4x4 tiles per wave ----
        #pragma unroll
        for (int ks = 0; ks < 2; ++ks) {
            bf16x8 af[4], bf_[4];
            #pragma unroll
            for (int mi = 0; mi < 4; ++mi)
                af[mi] = *(const bf16x8*)&As[(wm * 64 + mi * 16 + li) * 64 + ks * 32 + g * 8];
            #pragma unroll
            for (int ni = 0; ni < 4; ++ni)
                bf_[ni] = *(const bf16x8*)&Bs[(wn * 64 + ni * 16 + li) * 64 + ks * 32 + g * 8];
            #pragma unroll
            for (int mi = 0; mi < 4; ++mi)
                #pragma unroll
                for (int ni = 0; ni < 4; ++ni)
                    acc[mi][ni] = __builtin_amdgcn_mfma_f32_16x16x32_bf16(
                        af[mi], bf_[ni], acc[mi][ni], 0, 0, 0);
        }
        __syncthreads();
    }

    #pragma unroll
    for (int mi = 0; mi < 4; ++mi)
    #pragma unroll
    for (int ni = 0; ni < 4; ++ni)
    #pragma unroll
    for (int r = 0; r < 4; ++r) {
        const int row = m0 + wm * 64 + mi * 16 + g * 4 + r;
        const int col = n0 + wn * 64 + ni * 16 + li;
        float v = acc[mi][ni][r] + bias[col];
        if (RES == 1) v += ((const float*)resv)[(size_t)row * N + col];
        if (RES == 2) v += bf2f(((const u16*)resv)[(size_t)row * N + col]);
        if (ACT == 1) v = 0.5f * v * (1.0f + erff(v * 0.70710678118f));
        if (OBF) ((u16*)Ov)[(size_t)row * N + col] = f2bf(v);
        else     ((float*)Ov)[(size_t)row * N + col] = v;
    }
}

// ---------------------------------------------------------------------------
// MFMA temporal attention. Block = (b,h), 4 waves; wave w owns Q rows
// [32w,32w+32). S=Q K^T via MFMA, in-register softmax (16-lane shfl),
// P -> LDS (overlays dead K), O = P V via MFMA with V stored transposed.
// Epilogue adds chan[b][:] broadcast and writes bf16 to merged.
// ---------------------------------------------------------------------------
__global__ __launch_bounds__(256) void attn_mfma_kernel(
    const u16* __restrict__ Q, const u16* __restrict__ K,
    const u16* __restrict__ V, const float* __restrict__ chan,
    u16* __restrict__ merged)
{
    __shared__ u16 pool[26112];          // 52,224 B
    u16* Ks = pool;                      // [128][72]   (dead after S)
    u16* Ps = pool;                      // [128][136]  overlays Ks
    u16* Vt = pool + 17408;              // [64][136]   V transposed
    const int b = blockIdx.x, h = blockIdx.y;
    const int tid = threadIdx.x, lane = tid & 63, w = tid >> 6;
    const int li = lane & 15, g = lane >> 4;
    const size_t gbase = (size_t)b * 128 * 512 + (size_t)h * 64;

    // stage K rows -> Ks[t][d] (pad 72); V -> Vt[d][t] (pad 136)
    #pragma unroll
    for (int i = 0; i < 4; ++i) {
        const int c = tid + i * 256;     // 0..1023
        const int t = c >> 3, dc = c & 7;
        bf16x8 kv = *(const bf16x8*)&K[gbase + (size_t)t * 512 + dc * 8];
        *(bf16x8*)&Ks[t * 72 + dc * 8] = kv;
        bf16x8 vv = *(const bf16x8*)&V[gbase + (size_t)t * 512 + dc * 8];
        #pragma unroll
        for (int j = 0; j < 8; ++j) Vt[(dc * 8 + j) * 136 + t] = (u16)vv[j];
    }
    // Q fragments from global
    bf16x8 qf[2][2];
    #pragma unroll
    for (int mi = 0; mi < 2; ++mi)
        #pragma unroll
        for (int ks = 0; ks < 2; ++ks)
            qf[mi][ks] = *(const bf16x8*)
                &Q[gbase + (size_t)(w * 32 + mi * 16 + li) * 512 + ks * 32 + g * 8];
    __syncthreads();

    // S = Q K^T   (sacc[mi][nj]: rows mi*16+g*4+r, cols nj*16+li)
    f32x4 sacc[2][8] = {};
    #pragma unroll
    for (int nj = 0; nj < 8; ++nj) {
        bf16x8 kf0 = *(const bf16x8*)&Ks[(nj * 16 + li) * 72 + g * 8];
        bf16x8 kf1 = *(const bf16x8*)&Ks[(nj * 16 + li) * 72 + 32 + g * 8];
        #pragma unroll
        for (int mi = 0; mi < 2; ++mi) {
            sacc[mi][nj] = __builtin_amdgcn_mfma_f32_16x16x32_bf16(
                qf[mi][0], kf0, sacc[mi][nj], 0, 0, 0);
            sacc[mi][nj] = __builtin_amdgcn_mfma_f32_16x16x32_bf16(
                qf[mi][1], kf1, sacc[mi][nj], 0, 0, 0);
        }
    }
    // softmax: scale, row-max, exp, row-sum (rows live in 16-lane groups)
    float linv[2][4];
    #pragma unroll
    for (int mi = 0; mi < 2; ++mi)
    #pragma unroll
    for (int r = 0; r < 4; ++r) {
        float mx = -1e30f;
        #pragma unroll
        for (int nj = 0; nj < 8; ++nj) {
            sacc[mi][nj][r] *= 0.125f;
            mx = fmaxf(mx, sacc[mi][nj][r]);
        }
        mx = fmaxf(mx, __shfl_xor(mx, 1));
        mx = fmaxf(mx, __shfl_xor(mx, 2));
        mx = fmaxf(mx, __shfl_xor(mx, 4));
        mx = fmaxf(mx, __shfl_xor(mx, 8));
        float l = 0.f;
        #pragma unroll
        for (int nj = 0; nj < 8; ++nj) {
            float p = __expf(sacc[mi][nj][r] - mx);
            sacc[mi][nj][r] = p;
            l += p;
        }
        l += __shfl_xor(l, 1);
        l += __shfl_xor(l, 2);
        l += __shfl_xor(l, 4);
        l += __shfl_xor(l, 8);
        linv[mi][r] = 1.f / l;
    }
    __syncthreads();   // all waves done reading Ks
    // write P (bf16) to Ps
    #pragma unroll
    for (int mi = 0; mi < 2; ++mi)
    #pragma unroll
    for (int r = 0; r < 4; ++r)
        #pragma unroll
        for (int nj = 0; nj < 8; ++nj)
            Ps[(w * 32 + mi * 16 + g * 4 + r) * 136 + nj * 16 + li] =
                f2bf(sacc[mi][nj][r]);
    __syncthreads();

    // O = P V
    f32x4 oacc[2][4] = {};
    #pragma unroll
    for (int ks = 0; ks < 4; ++ks) {
        bf16x8 pf[2];
        #pragma unroll
        for (int mi = 0; mi < 2; ++mi)
            pf[mi] = *(const bf16x8*)&Ps[(w * 32 + mi * 16 + li) * 136 + ks * 32 + g * 8];
        #pragma unroll
        for (int ni = 0; ni < 4; ++ni) {
            bf16x8 vf = *(const bf16x8*)&Vt[(ni * 16 + li) * 136 + ks * 32 + g * 8];
            #pragma unroll
            for (int mi = 0; mi < 2; ++mi)
                oacc[mi][ni] = __builtin_amdgcn_mfma_f32_16x16x32_bf16(
                    pf[mi], vf, oacc[mi][ni], 0, 0, 0);
        }
    }
    // epilogue: normalize, add chan, write bf16
    #pragma unroll
    for (int mi = 0; mi < 2; ++mi)
    #pragma unroll
    for (int ni = 0; ni < 4; ++ni)
    #pragma unroll
    for (int r = 0; r < 4; ++r) {
        const int row = w * 32 + mi * 16 + g * 4 + r;
        const int col = ni * 16 + li;
        float v = oacc[mi][ni][r] * linv[mi][r] +
                  chan[(size_t)b * 512 + h * 64 + col];
        merged[gbase + (size_t)row * 512 + col] = f2bf(v);
    }
}

// ---------------------------------------------------------------------------
// Channel-compression attention (unchanged; small). Keys j=c*128+t,
// values j=t*32+c. oc layout: [bs][q][h*64+d] f32.
// ---------------------------------------------------------------------------
__global__ __launch_bounds__(512) void chan_oc_kernel(
    const u16* __restrict__ K, const u16* __restrict__ V,
    const float* __restrict__ router, float* __restrict__ oc)
{
    const int bs = blockIdx.x, h = blockIdx.y;
    const int qrow = threadIdx.x >> 6;
    const int lane = threadIdx.x & 63;

    float rq[64];
    {
        const float* rp = &router[(size_t)(h * 8 + qrow) * 64];
        #pragma unroll
        for (int d = 0; d < 64; d += 4) {
            float4 t = *(const float4*)&rp[d];
            rq[d] = t.x; rq[d + 1] = t.y; rq[d + 2] = t.z; rq[d + 3] = t.w;
        }
    }
    float m = -1e30f, l = 0.f;
    float o[64];
    #pragma unroll
    for (int d = 0; d < 64; ++d) o[d] = 0.f;

    for (int it = 0; it < 64; ++it) {
        int j = it * 64 + lane;
        int kc = j >> 7, kt = j & 127;
        const u16* kp = &K[((size_t)((bs * 32 + kc) * 128 + kt)) * 512 + h * 64];
        float s0 = 0.f, s1 = 0.f, s2 = 0.f, s3 = 0.f;
        #pragma unroll
        for (int d = 0; d < 64; d += 8) {
            bf16x8 t = *(const bf16x8*)&kp[d];
            s0 += rq[d + 0] * bf2f((u16)t[0]);
            s1 += rq[d + 1] * bf2f((u16)t[1]);
            s2 += rq[d + 2] * bf2f((u16)t[2]);
            s3 += rq[d + 3] * bf2f((u16)t[3]);
            s0 += rq[d + 4] * bf2f((u16)t[4]);
            s1 += rq[d + 5] * bf2f((u16)t[5]);
            s2 += rq[d + 6] * bf2f((u16)t[6]);
            s3 += rq[d + 7] * bf2f((u16)t[7]);
        }
        float s = ((s0 + s1) + (s2 + s3)) * 0.125f;
        int vcc = j & 31, vt = j >> 5;
        const u16* vp = &V[((size_t)((bs * 32 + vcc) * 128 + vt)) * 512 + h * 64];
        float mn = fmaxf(m, s);
        float al = __expf(m - mn);
        float p  = __expf(s - mn);
        l = l * al + p;
        #pragma unroll
        for (int d = 0; d < 64; d += 8) {
            bf16x8 t = *(const bf16x8*)&vp[d];
            #pragma unroll
            for (int jj = 0; jj < 8; ++jj)
                o[d + jj] = o[d + jj] * al + p * bf2f((u16)t[jj]);
        }
        m = mn;
    }
    #pragma unroll
    for (int off = 1; off < 64; off <<= 1) {
        float m2 = __shfl_xor(m, off);
        float l2 = __shfl_xor(l, off);
        float mn = fmaxf(m, m2);
        float a1 = __expf(m - mn), a2 = __expf(m2 - mn);
        l = l * a1 + l2 * a2;
        #pragma unroll
        for (int d = 0; d < 64; ++d) {
            float o2 = __shfl_xor(o[d], off);
            o[d] = o[d] * a1 + o2 * a2;
        }
        m = mn;
    }
    if (lane == 0) {
        float inv = 1.f / l;
        float* op = &oc[((size_t)bs * 8 + qrow) * 512 + h * 64];
        #pragma unroll
        for (int d = 0; d < 64; ++d) op[d] = o[d] * inv;
    }
}

__global__ __launch_bounds__(512) void chan_combine_kernel(
    const float* __restrict__ oc, const float* __restrict__ pos,
    const float* __restrict__ mexp, float* __restrict__ chan)
{
    const int b = blockIdx.x;
    const int bs = b >> 5, c = b & 31;
    const int d = threadIdx.x;
    float acc = 0.f;
    #pragma unroll
    for (int q = 0; q < 8; ++q)
        acc += mexp[c * 8 + q] *
               (oc[((size_t)bs * 8 + q) * 512 + d] + pos[q * 512 + d]);
    chan[(size_t)b * 512 + d] = acc;
}

// LayerNorm over 512. One wave per row, 4 rows/block. OBF: 1 = bf16 out.
template<int OBF>
__global__ __launch_bounds__(256) void ln_kernel(
    const float* __restrict__ in, const float* __restrict__ g,
    const float* __restrict__ bb, void* __restrict__ out)
{
    const size_t row = (size_t)blockIdx.x * 4 + (threadIdx.x >> 6);
    const int t = threadIdx.x & 63;
    const float* p = in + row * 512;
    float4 v0 = *(const float4*)(p + t * 4);
    float4 v1 = *(const float4*)(p + 256 + t * 4);
    float s = (v0.x + v0.y) + (v0.z + v0.w) + (v1.x + v1.y) + (v1.z + v1.w);
    #pragma unroll
    for (int off = 1; off < 64; off <<= 1) s += __shfl_xor(s, off);
    const float mean = s * (1.0f / 512.0f);
    float a, ss = 0.f;
    a = v0.x - mean; ss += a * a;  a = v0.y - mean; ss += a * a;
    a = v0.z - mean; ss += a * a;  a = v0.w - mean; ss += a * a;
    a = v1.x - mean; ss += a * a;  a = v1.y - mean; ss += a * a;
    a = v1.z - mean; ss += a * a;  a = v1.w - mean; ss += a * a;
    #pragma unroll
    for (int off = 1; off < 64; off <<= 1) ss += __shfl_xor(ss, off);
    const float rstd = rsqrtf(ss * (1.0f / 512.0f) + 1e-5f);
    const int c0 = t * 4, c1 = 256 + t * 4;
    float4 g0 = *(const float4*)(g + c0), g1v = *(const float4*)(g + c1);
    float4 b0 = *(const float4*)(bb + c0), b1v = *(const float4*)(bb + c1);
    float r0 = (v0.x - mean) * rstd * g0.x + b0.x;
    float r1 = (v0.y - mean) * rstd * g0.y + b0.y;
    float r2 = (v0.z - mean) * rstd * g0.z + b0.z;
    float r3 = (v0.w - mean) * rstd * g0.w + b0.w;
    float r4 = (v1.x - mean) * rstd * g1v.x + b1v.x;
    float r5 = (v1.y - mean) * rstd * g1v.y + b1v.y;
    float r6 = (v1.z - mean) * rstd * g1v.z + b1v.z;
    float r7 = (v1.w - mean) * rstd * g1v.w + b1v.w;
    if (OBF) {
        u16* ob = (u16*)out + row * 512;
        uint2 u0, u1;
        u0.x = (u32)f2bf(r0) | ((u32)f2bf(r1) << 16);
        u0.y = (u32)f2bf(r2) | ((u32)f2bf(r3) << 16);
        u1.x = (u32)f2bf(r4) | ((u32)f2bf(r5) << 16);
        u1.y = (u32)f2bf(r6) | ((u32)f2bf(r7) << 16);
        *(uint2*)(ob + c0) = u0;
        *(uint2*)(ob + c1) = u1;
    } else {
        float* of = (float*)out + row * 512;
        *(float4*)(of + c0) = make_float4(r0, r1, r2, r3);
        *(float4*)(of + c1) = make_float4(r4, r5, r6, r7);
    }
}

// ---------------------------------------------------------------------------
extern "C" void kernel_launch(void* const* d_in, const int* in_sizes, int n_in,
                              void* d_out, int out_size, void* d_ws, size_t ws_size,
                              hipStream_t stream)
{
    const float* src    = (const float*)d_in[0];
    const float* Wq     = (const float*)d_in[1];
    const float* bq     = (const float*)d_in[2];
    const float* Wk     = (const float*)d_in[3];
    const float* bk     = (const float*)d_in[4];
    const float* Wv     = (const float*)d_in[5];
    const float* bv     = (const float*)d_in[6];
    const float* Wo     = (const float*)d_in[7];
    const float* bo     = (const float*)d_in[8];
    const float* router = (const float*)d_in[9];
    const float* mexp   = (const float*)d_in[10];
    const float* pos    = (const float*)d_in[11];
    const float* g1     = (const float*)d_in[12];
    const float* b1     = (const float*)d_in[13];
    const float* Wf1    = (const float*)d_in[14];
    const float* bf1    = (const float*)d_in[15];
    const float* Wf2    = (const float*)d_in[16];
    const float* bf2_   = (const float*)d_in[17];
    const float* g2     = (const float*)d_in[18];
    const float* b2     = (const float*)d_in[19];

    float* out = (float*)d_out;   // h1 / h2 / final (268 MB)

    char* ws = (char*)d_ws;
    // ws layout (bytes). Peak ~545.8 MB.
    u16*   Qb     = (u16*)(ws + 0);              // 134217728
    u16*   Kb     = (u16*)(ws + 134217728);      // 134217728
    u16*   Vb     = (u16*)(ws + 268435456);      // 134217728
    u16*   merged = (u16*)(ws + 402653184);      // 134217728
    float* oc     = (float*)(ws + 536870912);    // 524288
    float* chan   = (float*)(ws + 537395200);    // 2097152
    u16*   wqb    = (u16*)(ws + 539492352);      // 524288
    u16*   wkb    = (u16*)(ws + 540016640);      // 524288
    u16*   wvb    = (u16*)(ws + 540540928);      // 524288
    u16*   wob    = (u16*)(ws + 541065216);      // 524288
    u16*   wf1b   = (u16*)(ws + 541589504);      // 2097152
    u16*   wf2b   = (u16*)(ws + 543686656);      // 2097152 (ends 545783808)
    // overlays:
    u16*   xb     = (u16*)(ws + 0);              // 134217728 bf16 LN1 out (over Qb)
    u16*   gbuf   = (u16*)(ws + 268435456);      // 134217728 bf16 gelu chunk (over Vb)

    const dim3 blk(256);
    // weights f32 -> bf16 (grid = n/1024)
    conv_kernel<<<dim3(256),  blk, 0, stream>>>(Wq,  wqb);
    conv_kernel<<<dim3(256),  blk, 0, stream>>>(Wk,  wkb);
    conv_kernel<<<dim3(256),  blk, 0, stream>>>(Wv,  wvb);
    conv_kernel<<<dim3(256),  blk, 0, stream>>>(Wo,  wob);
    conv_kernel<<<dim3(1024), blk, 0, stream>>>(Wf1, wf1b);
    conv_kernel<<<dim3(1024), blk, 0, stream>>>(Wf2, wf2b);
    // QKV projections (f32 A reg-staged)
    gemm_kernel<0, 0, 1, 0><<<dim3(1024, 4), blk, 0, stream>>>(
        src, wqb, bq, nullptr, Qb, 131072, 512, 512);
    gemm_kernel<0, 0, 1, 0><<<dim3(1024, 4), blk, 0, stream>>>(
        src, wkb, bk, nullptr, Kb, 131072, 512, 512);
    gemm_kernel<0, 0, 1, 0><<<dim3(1024, 4), blk, 0, stream>>>(
        src, wvb, bv, nullptr, Vb, 131072, 512, 512);
    // channel path first (attn epilogue consumes chan)
    chan_oc_kernel<<<dim3(32, 8), dim3(512), 0, stream>>>(Kb, Vb, router, oc);
    chan_combine_kernel<<<dim3(1024), dim3(512), 0, stream>>>(oc, pos, mexp, chan);
    // temporal attention (+chan) -> merged bf16
    attn_mfma_kernel<<<dim3(1024, 8), blk, 0, stream>>>(Qb, Kb, Vb, chan, merged);
    // h1 = src + merged @ Wo^T + bo -> d_out f32
    gemm_kernel<1, 0, 0, 1><<<dim3(1024, 4), blk, 0, stream>>>(
        merged, wob, bo, src, out, 131072, 512, 512);
    // x = LN1(h1) -> bf16
    ln_kernel<1><<<dim3(32768), blk, 0, stream>>>(out, g1, b1, xb);
    // FF in 4 chunks of 32768 rows
    for (int c = 0; c < 4; ++c) {
        const size_t off = (size_t)c * 32768 * 512;
        gemm_kernel<1, 1, 1, 0><<<dim3(256, 16), blk, 0, stream>>>(
            xb + off, wf1b, bf1, nullptr, gbuf, 32768, 2048, 512);
        gemm_kernel<1, 0, 0, 2><<<dim3(256, 4), blk, 0, stream>>>(
            gbuf, wf2b, bf2_, xb + off, out + off, 32768, 512, 2048);
    }
    // out = LN2(h2) in place
    ln_kernel<0><<<dim3(32768), blk, 0, stream>>>(out, g2, b2, out);
}

// Round 5
// 2146.044 us; speedup vs baseline: 2.2183x; 1.1614x over previous
//
#include <hip/hip_runtime.h>
#include <math.h>

typedef unsigned short u16;
typedef unsigned int u32;
typedef __attribute__((ext_vector_type(8))) short bf16x8;
typedef __attribute__((ext_vector_type(4))) float f32x4;

__device__ __forceinline__ float bf2f(u16 u) {
    union { u32 i; float f; } x; x.i = ((u32)u) << 16; return x.f;
}
__device__ __forceinline__ u16 f2bf(float f) {
    union { float f; u32 i; } x; x.f = f;
    u32 i = x.i;
    return (u16)((i + 0x7FFFu + ((i >> 16) & 1u)) >> 16);
}
__device__ __forceinline__ void async_copy16(void* lds, const void* g) {
    __builtin_amdgcn_global_load_lds(
        (const __attribute__((address_space(1))) void*)g,
        (__attribute__((address_space(3))) void*)lds, 16, 0, 0);
}

// f32 -> bf16 bulk convert; n must be divisible by 1024; grid = n/1024
__global__ __launch_bounds__(256) void conv_kernel(
    const float* __restrict__ in, u16* __restrict__ out)
{
    const int i = (blockIdx.x * 256 + threadIdx.x) * 4;
    float4 v = *(const float4*)&in[i];
    u32 lo = (u32)f2bf(v.x) | ((u32)f2bf(v.y) << 16);
    u32 hi = (u32)f2bf(v.z) | ((u32)f2bf(v.w) << 16);
    *(uint2*)&out[i] = make_uint2(lo, hi);
}

// pack bq,bk,bv -> [1536] f32; grid=6
__global__ __launch_bounds__(256) void pack_bias_kernel(
    const float* __restrict__ a, const float* __restrict__ b,
    const float* __restrict__ c, float* __restrict__ out)
{
    const int i = blockIdx.x * 256 + threadIdx.x;
    out[i] = i < 512 ? a[i] : (i < 1024 ? b[i - 512] : c[i - 1024]);
}

// ---------------------------------------------------------------------------
// 128x128-tile MFMA GEMM (m97 structure): C[M,N] = act(A @ B^T + bias)(+res)
// B bf16 [N,K] staged via global_load_lds.
// AMODE: 0 = A f32 (reg-stage+convert), 1 = A bf16 (global_load_lds)
// ACT: 1 = exact GELU. OBF: 1 = bf16 out. RES: 0 none, 1 f32, 2 bf16.
// NSPLIT: 1 = N==1536 QKV mode, write cols [0,512) -> Ov, [512,1024) -> O2,
//         [1024,1536) -> O3 (each [M,512] bf16).
// ---------------------------------------------------------------------------
template<int AMODE, int ACT, int OBF, int RES, int NSPLIT>
__global__ __launch_bounds__(256) void gemm_kernel(
    const void* __restrict__ Av, const u16* __restrict__ B,
    const float* __restrict__ bias, const void* __restrict__ resv,
    void* __restrict__ Ov, u16* __restrict__ O2, u16* __restrict__ O3,
    int M, int N, int K)
{
    __shared__ u16 As[128 * 64];
    __shared__ u16 Bs[128 * 64];
    const int tid = threadIdx.x;
    const int m0 = blockIdx.x * 128, n0 = blockIdx.y * 128;
    const int lane = tid & 63;
    const int wm = (tid >> 7), wn = (tid >> 6) & 1;     // 2x2 waves
    const int li = lane & 15, g = lane >> 4;

    f32x4 acc[4][4] = {};

    for (int k0 = 0; k0 < K; k0 += 64) {
        {
            const int wbase = tid & 192;                 // wave*64
            #pragma unroll
            for (int i = 0; i < 4; ++i) {
                const int c = i * 256 + tid;             // chunk 0..1023
                const int row = c >> 3, cc = c & 7;
                const u16* gp = &B[(size_t)(n0 + row) * K + k0 + cc * 8];
                async_copy16(&Bs[(size_t)(i * 256 + wbase) * 8], gp);
            }
        }
        if (AMODE == 1) {
            const u16* Ab = (const u16*)Av;
            const int wbase = tid & 192;
            #pragma unroll
            for (int i = 0; i < 4; ++i) {
                const int c = i * 256 + tid;
                const int row = c >> 3, cc = c & 7;
                const u16* gp = &Ab[(size_t)(m0 + row) * K + k0 + cc * 8];
                async_copy16(&As[(size_t)(i * 256 + wbase) * 8], gp);
            }
        } else {
            const float* Af = (const float*)Av;
            #pragma unroll
            for (int i = 0; i < 8; ++i) {
                const int c = i * 256 + tid;             // f32-quad 0..2047
                const int row = c >> 4, qc = c & 15;
                float4 v = *(const float4*)&Af[(size_t)(m0 + row) * K + k0 + qc * 4];
                u32 lo = (u32)f2bf(v.x) | ((u32)f2bf(v.y) << 16);
                u32 hi = (u32)f2bf(v.z) | ((u32)f2bf(v.w) << 16);
                *(uint2*)&As[row * 64 + qc * 4] = make_uint2(lo, hi);
            }
        }
        __syncthreads();
        #pragma unroll
        for (int ks = 0; ks < 2; ++ks) {
            bf16x8 af[4], bf_[4];
            #pragma unroll
            for (int mi = 0; mi < 4; ++mi)
                af[mi] = *(const bf16x8*)&As[(wm * 64 + mi * 16 + li) * 64 + ks * 32 + g * 8];
            #pragma unroll
            for (int ni = 0; ni < 4; ++ni)
                bf_[ni] = *(const bf16x8*)&Bs[(wn * 64 + ni * 16 + li) * 64 + ks * 32 + g * 8];
            #pragma unroll
            for (int mi = 0; mi < 4; ++mi)
                #pragma unroll
                for (int ni = 0; ni < 4; ++ni)
                    acc[mi][ni] = __builtin_amdgcn_mfma_f32_16x16x32_bf16(
                        af[mi], bf_[ni], acc[mi][ni], 0, 0, 0);
        }
        __syncthreads();
    }

    #pragma unroll
    for (int mi = 0; mi < 4; ++mi)
    #pragma unroll
    for (int ni = 0; ni < 4; ++ni) {
        const int colb = n0 + wn * 64 + ni * 16;
        #pragma unroll
        for (int r = 0; r < 4; ++r) {
            const int row = m0 + wm * 64 + mi * 16 + g * 4 + r;
            const int col = colb + li;
            float v = acc[mi][ni][r] + bias[col];
            if (RES == 1) v += ((const float*)resv)[(size_t)row * N + col];
            if (RES == 2) v += bf2f(((const u16*)resv)[(size_t)row * N + col]);
            if (ACT == 1) v = 0.5f * v * (1.0f + erff(v * 0.70710678118f));
            if (NSPLIT == 1) {
                const int sec = colb >> 9;
                u16* dst = sec == 0 ? (u16*)Ov : (sec == 1 ? O2 : O3);
                dst[(size_t)row * 512 + (col & 511)] = f2bf(v);
            } else if (OBF) {
                ((u16*)Ov)[(size_t)row * N + col] = f2bf(v);
            } else {
                ((float*)Ov)[(size_t)row * N + col] = v;
            }
        }
    }
}

// ---------------------------------------------------------------------------
// MFMA temporal attention. Block = (b,h), 4 waves; wave w owns Q rows
// [32w,32w+32). S=Q K^T via MFMA, in-register softmax (16-lane shfl),
// P -> LDS, O = P V via MFMA with V stored transposed.
// Epilogue adds chan[b][:] broadcast and writes bf16 to merged.
// ---------------------------------------------------------------------------
__global__ __launch_bounds__(256) void attn_mfma_kernel(
    const u16* __restrict__ Q, const u16* __restrict__ K,
    const u16* __restrict__ V, const float* __restrict__ chan,
    u16* __restrict__ merged)
{
    __shared__ u16 pool[26112];          // 52,224 B
    u16* Ks = pool;                      // [128][72]   (dead after S)
    u16* Ps = pool;                      // [128][136]  overlays Ks
    u16* Vt = pool + 17408;              // [64][136]   V transposed
    const int b = blockIdx.x, h = blockIdx.y;
    const int tid = threadIdx.x, lane = tid & 63, w = tid >> 6;
    const int li = lane & 15, g = lane >> 4;
    const size_t gbase = (size_t)b * 128 * 512 + (size_t)h * 64;

    #pragma unroll
    for (int i = 0; i < 4; ++i) {
        const int c = tid + i * 256;     // 0..1023
        const int t = c >> 3, dc = c & 7;
        bf16x8 kv = *(const bf16x8*)&K[gbase + (size_t)t * 512 + dc * 8];
        *(bf16x8*)&Ks[t * 72 + dc * 8] = kv;
        bf16x8 vv = *(const bf16x8*)&V[gbase + (size_t)t * 512 + dc * 8];
        #pragma unroll
        for (int j = 0; j < 8; ++j) Vt[(dc * 8 + j) * 136 + t] = (u16)vv[j];
    }
    bf16x8 qf[2][2];
    #pragma unroll
    for (int mi = 0; mi < 2; ++mi)
        #pragma unroll
        for (int ks = 0; ks < 2; ++ks)
            qf[mi][ks] = *(const bf16x8*)
                &Q[gbase + (size_t)(w * 32 + mi * 16 + li) * 512 + ks * 32 + g * 8];
    __syncthreads();

    f32x4 sacc[2][8] = {};
    #pragma unroll
    for (int nj = 0; nj < 8; ++nj) {
        bf16x8 kf0 = *(const bf16x8*)&Ks[(nj * 16 + li) * 72 + g * 8];
        bf16x8 kf1 = *(const bf16x8*)&Ks[(nj * 16 + li) * 72 + 32 + g * 8];
        #pragma unroll
        for (int mi = 0; mi < 2; ++mi) {
            sacc[mi][nj] = __builtin_amdgcn_mfma_f32_16x16x32_bf16(
                qf[mi][0], kf0, sacc[mi][nj], 0, 0, 0);
            sacc[mi][nj] = __builtin_amdgcn_mfma_f32_16x16x32_bf16(
                qf[mi][1], kf1, sacc[mi][nj], 0, 0, 0);
        }
    }
    float linv[2][4];
    #pragma unroll
    for (int mi = 0; mi < 2; ++mi)
    #pragma unroll
    for (int r = 0; r < 4; ++r) {
        float mx = -1e30f;
        #pragma unroll
        for (int nj = 0; nj < 8; ++nj) {
            sacc[mi][nj][r] *= 0.125f;
            mx = fmaxf(mx, sacc[mi][nj][r]);
        }
        mx = fmaxf(mx, __shfl_xor(mx, 1));
        mx = fmaxf(mx, __shfl_xor(mx, 2));
        mx = fmaxf(mx, __shfl_xor(mx, 4));
        mx = fmaxf(mx, __shfl_xor(mx, 8));
        float l = 0.f;
        #pragma unroll
        for (int nj = 0; nj < 8; ++nj) {
            float p = __expf(sacc[mi][nj][r] - mx);
            sacc[mi][nj][r] = p;
            l += p;
        }
        l += __shfl_xor(l, 1);
        l += __shfl_xor(l, 2);
        l += __shfl_xor(l, 4);
        l += __shfl_xor(l, 8);
        linv[mi][r] = 1.f / l;
    }
    __syncthreads();
    #pragma unroll
    for (int mi = 0; mi < 2; ++mi)
    #pragma unroll
    for (int r = 0; r < 4; ++r)
        #pragma unroll
        for (int nj = 0; nj < 8; ++nj)
            Ps[(w * 32 + mi * 16 + g * 4 + r) * 136 + nj * 16 + li] =
                f2bf(sacc[mi][nj][r]);
    __syncthreads();

    f32x4 oacc[2][4] = {};
    #pragma unroll
    for (int ks = 0; ks < 4; ++ks) {
        bf16x8 pf[2];
        #pragma unroll
        for (int mi = 0; mi < 2; ++mi)
            pf[mi] = *(const bf16x8*)&Ps[(w * 32 + mi * 16 + li) * 136 + ks * 32 + g * 8];
        #pragma unroll
        for (int ni = 0; ni < 4; ++ni) {
            bf16x8 vf = *(const bf16x8*)&Vt[(ni * 16 + li) * 136 + ks * 32 + g * 8];
            #pragma unroll
            for (int mi = 0; mi < 2; ++mi)
                oacc[mi][ni] = __builtin_amdgcn_mfma_f32_16x16x32_bf16(
                    pf[mi], vf, oacc[mi][ni], 0, 0, 0);
        }
    }
    #pragma unroll
    for (int mi = 0; mi < 2; ++mi)
    #pragma unroll
    for (int ni = 0; ni < 4; ++ni)
    #pragma unroll
    for (int r = 0; r < 4; ++r) {
        const int row = w * 32 + mi * 16 + g * 4 + r;
        const int col = ni * 16 + li;
        float v = oacc[mi][ni][r] * linv[mi][r] +
                  chan[(size_t)b * 512 + h * 64 + col];
        merged[gbase + (size_t)row * 512 + col] = f2bf(v);
    }
}

// ---------------------------------------------------------------------------
// Channel-compression attention v2. Block = (bs,h), 1024 threads (16 waves).
// Phase 1: S = router @ K^T via MFMA -> LDS S[8][4096] f32 (scaled).
//   Key index j = c*128 + t (channel-major flatten).
// Phase 2a: p = exp(s) (no max-sub: |s| <= ~6), per-q row-sum -> linv.
// Phase 2b: stream V rows linearly (row = c*128+t contiguous in memory);
//   P index j = t*32 + c (time-major flatten). VALU accumulate, LDS-atomic
//   cross-wave reduce.
// oc layout: [bs][q][h*64+d] f32.
// ---------------------------------------------------------------------------
__global__ __launch_bounds__(1024) void chan_oc_kernel(
    const u16* __restrict__ K, const u16* __restrict__ V,
    const u16* __restrict__ router_bf, float* __restrict__ oc)
{
    __shared__ float S[8 * 4096];        // 131072 B
    __shared__ float o_final[8 * 64];    // 2048 B
    __shared__ float linv[8];
    const int bs = blockIdx.x, h = blockIdx.y;
    const int tid = threadIdx.x, lane = tid & 63, w = tid >> 6;  // 16 waves
    const int li = lane & 15, g = lane >> 4;

    if (tid < 512) o_final[tid] = 0.f;

    // A-frags: router rows (q=li, valid q<8), k-chunks ks*32+g*8
    bf16x8 af[2];
    #pragma unroll
    for (int ks = 0; ks < 2; ++ks) {
        bf16x8 t = {};
        if (li < 8) t = *(const bf16x8*)&router_bf[(h * 8 + li) * 64 + ks * 32 + g * 8];
        af[ks] = t;
    }
    // scores: wave w -> j-tiles [w*16, w*16+16)
    #pragma unroll 4
    for (int n = w * 16; n < w * 16 + 16; ++n) {
        f32x4 acc = {};
        #pragma unroll
        for (int ks = 0; ks < 2; ++ks) {
            const int j = n * 16 + li;
            const int kc = j >> 7, kt = j & 127;
            bf16x8 bf_ = *(const bf16x8*)
                &K[((size_t)((bs * 32 + kc) * 128 + kt)) * 512 + h * 64 + ks * 32 + g * 8];
            acc = __builtin_amdgcn_mfma_f32_16x16x32_bf16(af[ks], bf_, acc, 0, 0, 0);
        }
        if (g < 2) {
            #pragma unroll
            for (int r = 0; r < 4; ++r)
                S[(g * 4 + r) * 4096 + n * 16 + li] = acc[r] * 0.125f;
        }
    }
    __syncthreads();
    // exp + row-sum (wave w<8 owns q=w)
    if (w < 8) {
        float l = 0.f;
        #pragma unroll 8
        for (int i = 0; i < 64; ++i) {
            float p = __expf(S[w * 4096 + i * 64 + lane]);
            S[w * 4096 + i * 64 + lane] = p;
            l += p;
        }
        #pragma unroll
        for (int off = 1; off < 64; off <<= 1) l += __shfl_xor(l, off);
        if (lane == 0) linv[w] = 1.f / l;
    }
    __syncthreads();
    // PV stream: wave w -> V rows [w*256, w*256+256), 4 rows/iter (g picks row)
    float o[8][4] = {};
    for (int it = 0; it < 64; ++it) {
        const int row = w * 256 + it * 4 + g;        // = c*128 + t
        const int j = (row & 127) * 32 + (row >> 7); // P index (t*32+c)
        const uint2 vv = *(const uint2*)
            &V[((size_t)bs * 4096 + row) * 512 + h * 64 + li * 4];
        const float v0 = bf2f((u16)(vv.x & 0xffff)), v1 = bf2f((u16)(vv.x >> 16));
        const float v2 = bf2f((u16)(vv.y & 0xffff)), v3 = bf2f((u16)(vv.y >> 16));
        #pragma unroll
        for (int q = 0; q < 8; ++q) {
            const float p = S[q * 4096 + j];
            o[q][0] += p * v0; o[q][1] += p * v1;
            o[q][2] += p * v2; o[q][3] += p * v3;
        }
    }
    #pragma unroll
    for (int q = 0; q < 8; ++q)
        #pragma unroll
        for (int i = 0; i < 4; ++i) {
            float v = o[q][i];
            v += __shfl_xor(v, 16);
            v += __shfl_xor(v, 32);
            if (g == 0) atomicAdd(&o_final[q * 64 + li * 4 + i], v);
        }
    __syncthreads();
    if (tid < 512) {
        const int q = tid >> 6, d = tid & 63;
        oc[((size_t)bs * 8 + q) * 512 + h * 64 + d] = o_final[q * 64 + d] * linv[q];
    }
}

__global__ __launch_bounds__(512) void chan_combine_kernel(
    const float* __restrict__ oc, const float* __restrict__ pos,
    const float* __restrict__ mexp, float* __restrict__ chan)
{
    const int b = blockIdx.x;
    const int bs = b >> 5, c = b & 31;
    const int d = threadIdx.x;
    float acc = 0.f;
    #pragma unroll
    for (int q = 0; q < 8; ++q)
        acc += mexp[c * 8 + q] *
               (oc[((size_t)bs * 8 + q) * 512 + d] + pos[q * 512 + d]);
    chan[(size_t)b * 512 + d] = acc;
}

// LayerNorm over 512. One wave per row, 4 rows/block. OBF: 1 = bf16 out.
template<int OBF>
__global__ __launch_bounds__(256) void ln_kernel(
    const float* __restrict__ in, const float* __restrict__ g,
    const float* __restrict__ bb, void* __restrict__ out)
{
    const size_t row = (size_t)blockIdx.x * 4 + (threadIdx.x >> 6);
    const int t = threadIdx.x & 63;
    const float* p = in + row * 512;
    float4 v0 = *(const float4*)(p + t * 4);
    float4 v1 = *(const float4*)(p + 256 + t * 4);
    float s = (v0.x + v0.y) + (v0.z + v0.w) + (v1.x + v1.y) + (v1.z + v1.w);
    #pragma unroll
    for (int off = 1; off < 64; off <<= 1) s += __shfl_xor(s, off);
    const float mean = s * (1.0f / 512.0f);
    float a, ss = 0.f;
    a = v0.x - mean; ss += a * a;  a = v0.y - mean; ss += a * a;
    a = v0.z - mean; ss += a * a;  a = v0.w - mean; ss += a * a;
    a = v1.x - mean; ss += a * a;  a = v1.y - mean; ss += a * a;
    a = v1.z - mean; ss += a * a;  a = v1.w - mean; ss += a * a;
    #pragma unroll
    for (int off = 1; off < 64; off <<= 1) ss += __shfl_xor(ss, off);
    const float rstd = rsqrtf(ss * (1.0f / 512.0f) + 1e-5f);
    const int c0 = t * 4, c1 = 256 + t * 4;
    float4 g0 = *(const float4*)(g + c0), g1v = *(const float4*)(g + c1);
    float4 b0 = *(const float4*)(bb + c0), b1v = *(const float4*)(bb + c1);
    float r0 = (v0.x - mean) * rstd * g0.x + b0.x;
    float r1 = (v0.y - mean) * rstd * g0.y + b0.y;
    float r2 = (v0.z - mean) * rstd * g0.z + b0.z;
    float r3 = (v0.w - mean) * rstd * g0.w + b0.w;
    float r4 = (v1.x - mean) * rstd * g1v.x + b1v.x;
    float r5 = (v1.y - mean) * rstd * g1v.y + b1v.y;
    float r6 = (v1.z - mean) * rstd * g1v.z + b1v.z;
    float r7 = (v1.w - mean) * rstd * g1v.w + b1v.w;
    if (OBF) {
        u16* ob = (u16*)out + row * 512;
        uint2 u0, u1;
        u0.x = (u32)f2bf(r0) | ((u32)f2bf(r1) << 16);
        u0.y = (u32)f2bf(r2) | ((u32)f2bf(r3) << 16);
        u1.x = (u32)f2bf(r4) | ((u32)f2bf(r5) << 16);
        u1.y = (u32)f2bf(r6) | ((u32)f2bf(r7) << 16);
        *(uint2*)(ob + c0) = u0;
        *(uint2*)(ob + c1) = u1;
    } else {
        float* of = (float*)out + row * 512;
        *(float4*)(of + c0) = make_float4(r0, r1, r2, r3);
        *(float4*)(of + c1) = make_float4(r4, r5, r6, r7);
    }
}

// ---------------------------------------------------------------------------
extern "C" void kernel_launch(void* const* d_in, const int* in_sizes, int n_in,
                              void* d_out, int out_size, void* d_ws, size_t ws_size,
                              hipStream_t stream)
{
    const float* src    = (const float*)d_in[0];
    const float* Wq     = (const float*)d_in[1];
    const float* bq     = (const float*)d_in[2];
    const float* Wk     = (const float*)d_in[3];
    const float* bk     = (const float*)d_in[4];
    const float* Wv     = (const float*)d_in[5];
    const float* bv     = (const float*)d_in[6];
    const float* Wo     = (const float*)d_in[7];
    const float* bo     = (const float*)d_in[8];
    const float* router = (const float*)d_in[9];
    const float* mexp   = (const float*)d_in[10];
    const float* pos    = (const float*)d_in[11];
    const float* g1     = (const float*)d_in[12];
    const float* b1     = (const float*)d_in[13];
    const float* Wf1    = (const float*)d_in[14];
    const float* bf1    = (const float*)d_in[15];
    const float* Wf2    = (const float*)d_in[16];
    const float* bf2_   = (const float*)d_in[17];
    const float* g2     = (const float*)d_in[18];
    const float* b2     = (const float*)d_in[19];

    float* out = (float*)d_out;   // h1 / h2 / final (268 MB)

    char* ws = (char*)d_ws;
    // ws layout (bytes). Peak ~547.4 MB.
    u16*   Qb     = (u16*)(ws + 0);              // 134217728
    u16*   Kb     = (u16*)(ws + 134217728);      // 134217728
    u16*   Vb     = (u16*)(ws + 268435456);      // 134217728
    u16*   merged = (u16*)(ws + 402653184);      // 134217728
    float* oc     = (float*)(ws + 536870912);    // 524288
    float* chan   = (float*)(ws + 537395200);    // 2097152
    u16*   wob    = (u16*)(ws + 541065216);      // 524288
    u16*   wf1b   = (u16*)(ws + 541589504);      // 2097152
    u16*   wf2b   = (u16*)(ws + 543686656);      // 2097152
    u16*   wqkvb  = (u16*)(ws + 545783808);      // 1572864
    float* qkvbias= (float*)(ws + 547356672);    // 6144
    u16*   routbf = (u16*)(ws + 547362816);      // 8192 (ends 547371008)
    // overlays:
    u16*   srcb   = (u16*)(ws + 402653184);      // bf16 src (over merged; dead
                                                 //  before attn writes merged)
    u16*   xb     = (u16*)(ws + 0);              // bf16 LN1 out (over Qb)
    u16*   gbuf   = (u16*)(ws + 268435456);      // bf16 gelu chunk (over Vb)

    const dim3 blk(256);
    // conversions / packing
    conv_kernel<<<dim3(65536), blk, 0, stream>>>(src, srcb);
    conv_kernel<<<dim3(256),  blk, 0, stream>>>(Wq,  wqkvb);
    conv_kernel<<<dim3(256),  blk, 0, stream>>>(Wk,  wqkvb + 262144);
    conv_kernel<<<dim3(256),  blk, 0, stream>>>(Wv,  wqkvb + 524288);
    conv_kernel<<<dim3(256),  blk, 0, stream>>>(Wo,  wob);
    conv_kernel<<<dim3(1024), blk, 0, stream>>>(Wf1, wf1b);
    conv_kernel<<<dim3(1024), blk, 0, stream>>>(Wf2, wf2b);
    conv_kernel<<<dim3(4),    blk, 0, stream>>>(router, routbf);
    pack_bias_kernel<<<dim3(6), blk, 0, stream>>>(bq, bk, bv, qkvbias);
    // fused QKV projection (bf16 A fast path), split-write Q/K/V
    gemm_kernel<1, 0, 1, 0, 1><<<dim3(1024, 12), blk, 0, stream>>>(
        srcb, wqkvb, qkvbias, nullptr, Qb, Kb, Vb, 131072, 1536, 512);
    // channel path (attn epilogue consumes chan)
    chan_oc_kernel<<<dim3(32, 8), dim3(1024), 0, stream>>>(Kb, Vb, routbf, oc);
    chan_combine_kernel<<<dim3(1024), dim3(512), 0, stream>>>(oc, pos, mexp, chan);
    // temporal attention (+chan) -> merged bf16
    attn_mfma_kernel<<<dim3(1024, 8), blk, 0, stream>>>(Qb, Kb, Vb, chan, merged);
    // h1 = src + merged @ Wo^T + bo -> d_out f32
    gemm_kernel<1, 0, 0, 1, 0><<<dim3(1024, 4), blk, 0, stream>>>(
        merged, wob, bo, src, out, nullptr, nullptr, 131072, 512, 512);
    // x = LN1(h1) -> bf16
    ln_kernel<1><<<dim3(32768), blk, 0, stream>>>(out, g1, b1, xb);
    // FF in 4 chunks of 32768 rows
    for (int c = 0; c < 4; ++c) {
        const size_t off = (size_t)c * 32768 * 512;
        gemm_kernel<1, 1, 1, 0, 0><<<dim3(256, 16), blk, 0, stream>>>(
            xb + off, wf1b, bf1, nullptr, gbuf, nullptr, nullptr, 32768, 2048, 512);
        gemm_kernel<1, 0, 0, 2, 0><<<dim3(256, 4), blk, 0, stream>>>(
            gbuf, wf2b, bf2_, xb + off, out + off, nullptr, nullptr, 32768, 512, 2048);
    }
    // out = LN2(h2) in place
    ln_kernel<0><<<dim3(32768), blk, 0, stream>>>(out, g2, b2, out);
}

// Round 6
// 1814.037 us; speedup vs baseline: 2.6242x; 1.1830x over previous
//
#include <hip/hip_runtime.h>
#include <math.h>

typedef unsigned short u16;
typedef unsigned int u32;
typedef __attribute__((ext_vector_type(8))) short bf16x8;
typedef __attribute__((ext_vector_type(4))) float f32x4;

__device__ __forceinline__ float bf2f(u16 u) {
    union { u32 i; float f; } x; x.i = ((u32)u) << 16; return x.f;
}
__device__ __forceinline__ u16 f2bf(float f) {
    union { float f; u32 i; } x; x.f = f;
    u32 i = x.i;
    return (u16)((i + 0x7FFFu + ((i >> 16) & 1u)) >> 16);
}
__device__ __forceinline__ void async_copy16(void* lds, const void* g) {
    __builtin_amdgcn_global_load_lds(
        (const __attribute__((address_space(1))) void*)g,
        (__attribute__((address_space(3))) void*)lds, 16, 0, 0);
}

// f32 -> bf16 bulk convert; n must be divisible by 1024; grid = n/1024
__global__ __launch_bounds__(256) void conv_kernel(
    const float* __restrict__ in, u16* __restrict__ out)
{
    const int i = (blockIdx.x * 256 + threadIdx.x) * 4;
    float4 v = *(const float4*)&in[i];
    u32 lo = (u32)f2bf(v.x) | ((u32)f2bf(v.y) << 16);
    u32 hi = (u32)f2bf(v.z) | ((u32)f2bf(v.w) << 16);
    *(uint2*)&out[i] = make_uint2(lo, hi);
}

// pack bq,bk,bv -> [1536] f32; grid=6
__global__ __launch_bounds__(256) void pack_bias_kernel(
    const float* __restrict__ a, const float* __restrict__ b,
    const float* __restrict__ c, float* __restrict__ out)
{
    const int i = blockIdx.x * 256 + threadIdx.x;
    out[i] = i < 512 ? a[i] : (i < 1024 ? b[i - 512] : c[i - 1024]);
}

// ---------------------------------------------------------------------------
// 256x256-tile, 8-wave, double-buffered 2-phase MFMA GEMM.
// C[M,N] = act(A @ B^T + bias) (+res). A,B bf16; B = [N,K] weights.
// LDS chunk swizzle: 16B chunk cc of row r stored at position cc^(r&7)
// (linear LDS dest for global_load_lds; source address pre-swizzled;
//  reads apply the same XOR) -> 2-way max bank aliasing (free).
// ACT: 1 = exact GELU. OBF: 1 = bf16 out. RES: 0 none, 1 f32, 2 bf16.
// NSPLIT: 1 = N==1536 QKV mode (cols [0,512)->Ov, [512,1024)->O2, rest->O3).
// Grid: 1D, nwg = (M/256)*(N/256), XCD-swizzled, n-tile fastest.
// ---------------------------------------------------------------------------
template<int ACT, int OBF, int RES, int NSPLIT>
__global__ __launch_bounds__(512) void gemm256_kernel(
    const u16* __restrict__ Ag, const u16* __restrict__ Bg,
    const float* __restrict__ bias, const void* __restrict__ resv,
    void* __restrict__ Ov, u16* __restrict__ O2, u16* __restrict__ O3,
    int M, int N, int K)
{
    __shared__ u16 As[2][16384];   // [256][64] per buffer
    __shared__ u16 Bs[2][16384];
    const int tid = threadIdx.x;
    const int lane = tid & 63;
    const int wm = tid >> 8, wn = (tid >> 6) & 3;     // 2x4 waves
    const int li = lane & 15, g = lane >> 4;

    // XCD-aware bijective swizzle (nwg % 8 == 0 for all our launches)
    const int nwg = gridDim.x;
    const int wg = ((blockIdx.x & 7) * (nwg >> 3)) + (blockIdx.x >> 3);
    const int ntn = N >> 8;
    const int m0 = (wg / ntn) << 8;
    const int n0 = (wg % ntn) << 8;

    f32x4 acc[8][4] = {};

    const int nk = K >> 6;
    // prologue: stage tile 0 into buffer 0
    {
        #pragma unroll
        for (int i = 0; i < 4; ++i) {
            const int base = i * 512 + (tid & 448);
            const int L = base + lane;
            const int row = L >> 3;
            const int cc = (L & 7) ^ (row & 7);
            async_copy16(&As[0][base * 8], &Ag[(size_t)(m0 + row) * K + cc * 8]);
            async_copy16(&Bs[0][base * 8], &Bg[(size_t)(n0 + row) * K + cc * 8]);
        }
    }
    __syncthreads();

    for (int t = 0; t < nk; ++t) {
        const int cur = t & 1;
        if (t + 1 < nk) {
            const int k0 = (t + 1) << 6;
            #pragma unroll
            for (int i = 0; i < 4; ++i) {
                const int base = i * 512 + (tid & 448);
                const int L = base + lane;
                const int row = L >> 3;
                const int cc = (L & 7) ^ (row & 7);
                async_copy16(&As[cur ^ 1][base * 8],
                             &Ag[(size_t)(m0 + row) * K + k0 + cc * 8]);
                async_copy16(&Bs[cur ^ 1][base * 8],
                             &Bg[(size_t)(n0 + row) * K + k0 + cc * 8]);
            }
        }
        #pragma unroll
        for (int ks = 0; ks < 2; ++ks) {
            bf16x8 af[8], bf_[4];
            #pragma unroll
            for (int mi = 0; mi < 8; ++mi) {
                const int row = wm * 128 + mi * 16 + li;
                const int ch = (ks * 4 + g) ^ (row & 7);
                af[mi] = *(const bf16x8*)&As[cur][row * 64 + ch * 8];
            }
            #pragma unroll
            for (int ni = 0; ni < 4; ++ni) {
                const int row = wn * 64 + ni * 16 + li;
                const int ch = (ks * 4 + g) ^ (row & 7);
                bf_[ni] = *(const bf16x8*)&Bs[cur][row * 64 + ch * 8];
            }
            #pragma unroll
            for (int mi = 0; mi < 8; ++mi)
                #pragma unroll
                for (int ni = 0; ni < 4; ++ni)
                    acc[mi][ni] = __builtin_amdgcn_mfma_f32_16x16x32_bf16(
                        af[mi], bf_[ni], acc[mi][ni], 0, 0, 0);
        }
        __syncthreads();
    }

    #pragma unroll
    for (int mi = 0; mi < 8; ++mi)
    #pragma unroll
    for (int ni = 0; ni < 4; ++ni) {
        const int colb = n0 + wn * 64 + ni * 16;
        #pragma unroll
        for (int r = 0; r < 4; ++r) {
            const int row = m0 + wm * 128 + mi * 16 + g * 4 + r;
            const int col = colb + li;
            float v = acc[mi][ni][r] + bias[col];
            if (RES == 1) v += ((const float*)resv)[(size_t)row * N + col];
            if (RES == 2) v += bf2f(((const u16*)resv)[(size_t)row * N + col]);
            if (ACT == 1) v = 0.5f * v * (1.0f + erff(v * 0.70710678118f));
            if (NSPLIT == 1) {
                const int sec = colb >> 9;
                u16* dst = sec == 0 ? (u16*)Ov : (sec == 1 ? O2 : O3);
                dst[(size_t)row * 512 + (col & 511)] = f2bf(v);
            } else if (OBF) {
                ((u16*)Ov)[(size_t)row * N + col] = f2bf(v);
            } else {
                ((float*)Ov)[(size_t)row * N + col] = v;
            }
        }
    }
}

// ---------------------------------------------------------------------------
// MFMA temporal attention (unchanged from round 4/5 — verified).
// Block = (b,h), 4 waves. Epilogue adds chan broadcast, writes bf16.
// ---------------------------------------------------------------------------
__global__ __launch_bounds__(256) void attn_mfma_kernel(
    const u16* __restrict__ Q, const u16* __restrict__ K,
    const u16* __restrict__ V, const float* __restrict__ chan,
    u16* __restrict__ merged)
{
    __shared__ u16 pool[26112];          // 52,224 B
    u16* Ks = pool;                      // [128][72]   (dead after S)
    u16* Ps = pool;                      // [128][136]  overlays Ks
    u16* Vt = pool + 17408;              // [64][136]   V transposed
    const int b = blockIdx.x, h = blockIdx.y;
    const int tid = threadIdx.x, lane = tid & 63, w = tid >> 6;
    const int li = lane & 15, g = lane >> 4;
    const size_t gbase = (size_t)b * 128 * 512 + (size_t)h * 64;

    #pragma unroll
    for (int i = 0; i < 4; ++i) {
        const int c = tid + i * 256;     // 0..1023
        const int t = c >> 3, dc = c & 7;
        bf16x8 kv = *(const bf16x8*)&K[gbase + (size_t)t * 512 + dc * 8];
        *(bf16x8*)&Ks[t * 72 + dc * 8] = kv;
        bf16x8 vv = *(const bf16x8*)&V[gbase + (size_t)t * 512 + dc * 8];
        #pragma unroll
        for (int j = 0; j < 8; ++j) Vt[(dc * 8 + j) * 136 + t] = (u16)vv[j];
    }
    bf16x8 qf[2][2];
    #pragma unroll
    for (int mi = 0; mi < 2; ++mi)
        #pragma unroll
        for (int ks = 0; ks < 2; ++ks)
            qf[mi][ks] = *(const bf16x8*)
                &Q[gbase + (size_t)(w * 32 + mi * 16 + li) * 512 + ks * 32 + g * 8];
    __syncthreads();

    f32x4 sacc[2][8] = {};
    #pragma unroll
    for (int nj = 0; nj < 8; ++nj) {
        bf16x8 kf0 = *(const bf16x8*)&Ks[(nj * 16 + li) * 72 + g * 8];
        bf16x8 kf1 = *(const bf16x8*)&Ks[(nj * 16 + li) * 72 + 32 + g * 8];
        #pragma unroll
        for (int mi = 0; mi < 2; ++mi) {
            sacc[mi][nj] = __builtin_amdgcn_mfma_f32_16x16x32_bf16(
                qf[mi][0], kf0, sacc[mi][nj], 0, 0, 0);
            sacc[mi][nj] = __builtin_amdgcn_mfma_f32_16x16x32_bf16(
                qf[mi][1], kf1, sacc[mi][nj], 0, 0, 0);
        }
    }
    float linv[2][4];
    #pragma unroll
    for (int mi = 0; mi < 2; ++mi)
    #pragma unroll
    for (int r = 0; r < 4; ++r) {
        float mx = -1e30f;
        #pragma unroll
        for (int nj = 0; nj < 8; ++nj) {
            sacc[mi][nj][r] *= 0.125f;
            mx = fmaxf(mx, sacc[mi][nj][r]);
        }
        mx = fmaxf(mx, __shfl_xor(mx, 1));
        mx = fmaxf(mx, __shfl_xor(mx, 2));
        mx = fmaxf(mx, __shfl_xor(mx, 4));
        mx = fmaxf(mx, __shfl_xor(mx, 8));
        float l = 0.f;
        #pragma unroll
        for (int nj = 0; nj < 8; ++nj) {
            float p = __expf(sacc[mi][nj][r] - mx);
            sacc[mi][nj][r] = p;
            l += p;
        }
        l += __shfl_xor(l, 1);
        l += __shfl_xor(l, 2);
        l += __shfl_xor(l, 4);
        l += __shfl_xor(l, 8);
        linv[mi][r] = 1.f / l;
    }
    __syncthreads();
    #pragma unroll
    for (int mi = 0; mi < 2; ++mi)
    #pragma unroll
    for (int r = 0; r < 4; ++r)
        #pragma unroll
        for (int nj = 0; nj < 8; ++nj)
            Ps[(w * 32 + mi * 16 + g * 4 + r) * 136 + nj * 16 + li] =
                f2bf(sacc[mi][nj][r]);
    __syncthreads();

    f32x4 oacc[2][4] = {};
    #pragma unroll
    for (int ks = 0; ks < 4; ++ks) {
        bf16x8 pf[2];
        #pragma unroll
        for (int mi = 0; mi < 2; ++mi)
            pf[mi] = *(const bf16x8*)&Ps[(w * 32 + mi * 16 + li) * 136 + ks * 32 + g * 8];
        #pragma unroll
        for (int ni = 0; ni < 4; ++ni) {
            bf16x8 vf = *(const bf16x8*)&Vt[(ni * 16 + li) * 136 + ks * 32 + g * 8];
            #pragma unroll
            for (int mi = 0; mi < 2; ++mi)
                oacc[mi][ni] = __builtin_amdgcn_mfma_f32_16x16x32_bf16(
                    pf[mi], vf, oacc[mi][ni], 0, 0, 0);
        }
    }
    #pragma unroll
    for (int mi = 0; mi < 2; ++mi)
    #pragma unroll
    for (int ni = 0; ni < 4; ++ni)
    #pragma unroll
    for (int r = 0; r < 4; ++r) {
        const int row = w * 32 + mi * 16 + g * 4 + r;
        const int col = ni * 16 + li;
        float v = oacc[mi][ni][r] * linv[mi][r] +
                  chan[(size_t)b * 512 + h * 64 + col];
        merged[gbase + (size_t)row * 512 + col] = f2bf(v);
    }
}

// ---------------------------------------------------------------------------
// Channel-compression attention v2 (unchanged from round 5 — verified).
// ---------------------------------------------------------------------------
__global__ __launch_bounds__(1024) void chan_oc_kernel(
    const u16* __restrict__ K, const u16* __restrict__ V,
    const u16* __restrict__ router_bf, float* __restrict__ oc)
{
    __shared__ float S[8 * 4096];        // 131072 B
    __shared__ float o_final[8 * 64];    // 2048 B
    __shared__ float linv[8];
    const int bs = blockIdx.x, h = blockIdx.y;
    const int tid = threadIdx.x, lane = tid & 63, w = tid >> 6;  // 16 waves
    const int li = lane & 15, g = lane >> 4;

    if (tid < 512) o_final[tid] = 0.f;

    bf16x8 af[2];
    #pragma unroll
    for (int ks = 0; ks < 2; ++ks) {
        bf16x8 t = {};
        if (li < 8) t = *(const bf16x8*)&router_bf[(h * 8 + li) * 64 + ks * 32 + g * 8];
        af[ks] = t;
    }
    #pragma unroll 4
    for (int n = w * 16; n < w * 16 + 16; ++n) {
        f32x4 acc = {};
        #pragma unroll
        for (int ks = 0; ks < 2; ++ks) {
            const int j = n * 16 + li;
            const int kc = j >> 7, kt = j & 127;
            bf16x8 bf_ = *(const bf16x8*)
                &K[((size_t)((bs * 32 + kc) * 128 + kt)) * 512 + h * 64 + ks * 32 + g * 8];
            acc = __builtin_amdgcn_mfma_f32_16x16x32_bf16(af[ks], bf_, acc, 0, 0, 0);
        }
        if (g < 2) {
            #pragma unroll
            for (int r = 0; r < 4; ++r)
                S[(g * 4 + r) * 4096 + n * 16 + li] = acc[r] * 0.125f;
        }
    }
    __syncthreads();
    if (w < 8) {
        float l = 0.f;
        #pragma unroll 8
        for (int i = 0; i < 64; ++i) {
            float p = __expf(S[w * 4096 + i * 64 + lane]);
            S[w * 4096 + i * 64 + lane] = p;
            l += p;
        }
        #pragma unroll
        for (int off = 1; off < 64; off <<= 1) l += __shfl_xor(l, off);
        if (lane == 0) linv[w] = 1.f / l;
    }
    __syncthreads();
    float o[8][4] = {};
    for (int it = 0; it < 64; ++it) {
        const int row = w * 256 + it * 4 + g;        // = c*128 + t
        const int j = (row & 127) * 32 + (row >> 7); // P index (t*32+c)
        const uint2 vv = *(const uint2*)
            &V[((size_t)bs * 4096 + row) * 512 + h * 64 + li * 4];
        const float v0 = bf2f((u16)(vv.x & 0xffff)), v1 = bf2f((u16)(vv.x >> 16));
        const float v2 = bf2f((u16)(vv.y & 0xffff)), v3 = bf2f((u16)(vv.y >> 16));
        #pragma unroll
        for (int q = 0; q < 8; ++q) {
            const float p = S[q * 4096 + j];
            o[q][0] += p * v0; o[q][1] += p * v1;
            o[q][2] += p * v2; o[q][3] += p * v3;
        }
    }
    #pragma unroll
    for (int q = 0; q < 8; ++q)
        #pragma unroll
        for (int i = 0; i < 4; ++i) {
            float v = o[q][i];
            v += __shfl_xor(v, 16);
            v += __shfl_xor(v, 32);
            if (g == 0) atomicAdd(&o_final[q * 64 + li * 4 + i], v);
        }
    __syncthreads();
    if (tid < 512) {
        const int q = tid >> 6, d = tid & 63;
        oc[((size_t)bs * 8 + q) * 512 + h * 64 + d] = o_final[q * 64 + d] * linv[q];
    }
}

__global__ __launch_bounds__(512) void chan_combine_kernel(
    const float* __restrict__ oc, const float* __restrict__ pos,
    const float* __restrict__ mexp, float* __restrict__ chan)
{
    const int b = blockIdx.x;
    const int bs = b >> 5, c = b & 31;
    const int d = threadIdx.x;
    float acc = 0.f;
    #pragma unroll
    for (int q = 0; q < 8; ++q)
        acc += mexp[c * 8 + q] *
               (oc[((size_t)bs * 8 + q) * 512 + d] + pos[q * 512 + d]);
    chan[(size_t)b * 512 + d] = acc;
}

// LayerNorm over 512. One wave per row, 4 rows/block.
// IBF: 1 = bf16 input. OBF: 1 = bf16 out.
template<int IBF, int OBF>
__global__ __launch_bounds__(256) void ln_kernel(
    const void* __restrict__ inv, const float* __restrict__ g,
    const float* __restrict__ bb, void* __restrict__ out)
{
    const size_t row = (size_t)blockIdx.x * 4 + (threadIdx.x >> 6);
    const int t = threadIdx.x & 63;
    float4 v0, v1;
    if (IBF) {
        const u16* p = (const u16*)inv + row * 512;
        uint2 a = *(const uint2*)(p + t * 4);
        uint2 b = *(const uint2*)(p + 256 + t * 4);
        v0 = make_float4(bf2f((u16)(a.x & 0xffff)), bf2f((u16)(a.x >> 16)),
                         bf2f((u16)(a.y & 0xffff)), bf2f((u16)(a.y >> 16)));
        v1 = make_float4(bf2f((u16)(b.x & 0xffff)), bf2f((u16)(b.x >> 16)),
                         bf2f((u16)(b.y & 0xffff)), bf2f((u16)(b.y >> 16)));
    } else {
        const float* p = (const float*)inv + row * 512;
        v0 = *(const float4*)(p + t * 4);
        v1 = *(const float4*)(p + 256 + t * 4);
    }
    float s = (v0.x + v0.y) + (v0.z + v0.w) + (v1.x + v1.y) + (v1.z + v1.w);
    #pragma unroll
    for (int off = 1; off < 64; off <<= 1) s += __shfl_xor(s, off);
    const float mean = s * (1.0f / 512.0f);
    float a, ss = 0.f;
    a = v0.x - mean; ss += a * a;  a = v0.y - mean; ss += a * a;
    a = v0.z - mean; ss += a * a;  a = v0.w - mean; ss += a * a;
    a = v1.x - mean; ss += a * a;  a = v1.y - mean; ss += a * a;
    a = v1.z - mean; ss += a * a;  a = v1.w - mean; ss += a * a;
    #pragma unroll
    for (int off = 1; off < 64; off <<= 1) ss += __shfl_xor(ss, off);
    const float rstd = rsqrtf(ss * (1.0f / 512.0f) + 1e-5f);
    const int c0 = t * 4, c1 = 256 + t * 4;
    float4 g0 = *(const float4*)(g + c0), g1v = *(const float4*)(g + c1);
    float4 b0 = *(const float4*)(bb + c0), b1v = *(const float4*)(bb + c1);
    float r0 = (v0.x - mean) * rstd * g0.x + b0.x;
    float r1 = (v0.y - mean) * rstd * g0.y + b0.y;
    float r2 = (v0.z - mean) * rstd * g0.z + b0.z;
    float r3 = (v0.w - mean) * rstd * g0.w + b0.w;
    float r4 = (v1.x - mean) * rstd * g1v.x + b1v.x;
    float r5 = (v1.y - mean) * rstd * g1v.y + b1v.y;
    float r6 = (v1.z - mean) * rstd * g1v.z + b1v.z;
    float r7 = (v1.w - mean) * rstd * g1v.w + b1v.w;
    if (OBF) {
        u16* ob = (u16*)out + row * 512;
        uint2 u0, u1;
        u0.x = (u32)f2bf(r0) | ((u32)f2bf(r1) << 16);
        u0.y = (u32)f2bf(r2) | ((u32)f2bf(r3) << 16);
        u1.x = (u32)f2bf(r4) | ((u32)f2bf(r5) << 16);
        u1.y = (u32)f2bf(r6) | ((u32)f2bf(r7) << 16);
        *(uint2*)(ob + c0) = u0;
        *(uint2*)(ob + c1) = u1;
    } else {
        float* of = (float*)out + row * 512;
        *(float4*)(of + c0) = make_float4(r0, r1, r2, r3);
        *(float4*)(of + c1) = make_float4(r4, r5, r6, r7);
    }
}

// ---------------------------------------------------------------------------
extern "C" void kernel_launch(void* const* d_in, const int* in_sizes, int n_in,
                              void* d_out, int out_size, void* d_ws, size_t ws_size,
                              hipStream_t stream)
{
    const float* src    = (const float*)d_in[0];
    const float* Wq     = (const float*)d_in[1];
    const float* bq     = (const float*)d_in[2];
    const float* Wk     = (const float*)d_in[3];
    const float* bk     = (const float*)d_in[4];
    const float* Wv     = (const float*)d_in[5];
    const float* bv     = (const float*)d_in[6];
    const float* Wo     = (const float*)d_in[7];
    const float* bo     = (const float*)d_in[8];
    const float* router = (const float*)d_in[9];
    const float* mexp   = (const float*)d_in[10];
    const float* pos    = (const float*)d_in[11];
    const float* g1     = (const float*)d_in[12];
    const float* b1     = (const float*)d_in[13];
    const float* Wf1    = (const float*)d_in[14];
    const float* bf1    = (const float*)d_in[15];
    const float* Wf2    = (const float*)d_in[16];
    const float* bf2_   = (const float*)d_in[17];
    const float* g2     = (const float*)d_in[18];
    const float* b2     = (const float*)d_in[19];

    float* out = (float*)d_out;   // final f32 only (written by LN2)

    char* ws = (char*)d_ws;
    // ws layout (bytes). Peak ~547.4 MB (same as round 5 proven budget).
    u16*   Qb     = (u16*)(ws + 0);              // 134217728
    u16*   Kb     = (u16*)(ws + 134217728);      // 134217728
    u16*   Vb     = (u16*)(ws + 268435456);      // 134217728
    u16*   merged = (u16*)(ws + 402653184);      // 134217728
    float* oc     = (float*)(ws + 536870912);    // 524288
    float* chan   = (float*)(ws + 537395200);    // 2097152
    u16*   wob    = (u16*)(ws + 541065216);      // 524288
    u16*   wf1b   = (u16*)(ws + 541589504);      // 2097152
    u16*   wf2b   = (u16*)(ws + 543686656);      // 2097152
    u16*   wqkvb  = (u16*)(ws + 545783808);      // 1572864
    float* qkvbias= (float*)(ws + 547356672);    // 6144
    u16*   routbf = (u16*)(ws + 547362816);      // 8192 (ends 547371008)
    // overlays (liveness-checked):
    u16*   srcb   = (u16*)(ws + 402653184);      // bf16 src (over merged;
                                                 //  dead before attn writes)
    u16*   h1b    = (u16*)(ws + 134217728);      // bf16 h1 (over Kb; Kb dead
                                                 //  after attn/chan)
    u16*   xb     = (u16*)(ws + 0);              // bf16 LN1 out (over Qb)
    u16*   gbuf   = (u16*)(ws + 268435456);      // bf16 gelu chunk (over Vb)
    u16*   h2b    = (u16*)(ws + 402653184);      // bf16 h2 (over merged; dead
                                                 //  after Wo)

    const dim3 blk(256);
    const dim3 blk512(512);
    // conversions / packing
    conv_kernel<<<dim3(65536), blk, 0, stream>>>(src, srcb);
    conv_kernel<<<dim3(256),  blk, 0, stream>>>(Wq,  wqkvb);
    conv_kernel<<<dim3(256),  blk, 0, stream>>>(Wk,  wqkvb + 262144);
    conv_kernel<<<dim3(256),  blk, 0, stream>>>(Wv,  wqkvb + 524288);
    conv_kernel<<<dim3(256),  blk, 0, stream>>>(Wo,  wob);
    conv_kernel<<<dim3(1024), blk, 0, stream>>>(Wf1, wf1b);
    conv_kernel<<<dim3(1024), blk, 0, stream>>>(Wf2, wf2b);
    conv_kernel<<<dim3(4),    blk, 0, stream>>>(router, routbf);
    pack_bias_kernel<<<dim3(6), blk, 0, stream>>>(bq, bk, bv, qkvbias);
    // fused QKV projection: grid (131072/256)*(1536/256) = 512*6 = 3072
    gemm256_kernel<0, 1, 0, 1><<<dim3(3072), blk512, 0, stream>>>(
        srcb, wqkvb, qkvbias, nullptr, Qb, Kb, Vb, 131072, 1536, 512);
    // channel path (attn epilogue consumes chan)
    chan_oc_kernel<<<dim3(32, 8), dim3(1024), 0, stream>>>(Kb, Vb, routbf, oc);
    chan_combine_kernel<<<dim3(1024), dim3(512), 0, stream>>>(oc, pos, mexp, chan);
    // temporal attention (+chan) -> merged bf16
    attn_mfma_kernel<<<dim3(1024, 8), blk, 0, stream>>>(Qb, Kb, Vb, chan, merged);
    // h1 = src + merged @ Wo^T + bo -> h1b bf16; grid 512*2 = 1024
    gemm256_kernel<0, 1, 1, 0><<<dim3(1024), blk512, 0, stream>>>(
        merged, wob, bo, src, h1b, nullptr, nullptr, 131072, 512, 512);
    // x = LN1(h1) -> bf16
    ln_kernel<1, 1><<<dim3(32768), blk, 0, stream>>>(h1b, g1, b1, xb);
    // FF in 4 chunks of 32768 rows
    for (int c = 0; c < 4; ++c) {
        const size_t off = (size_t)c * 32768 * 512;
        const size_t off2k = (size_t)c * 32768 * 2048;
        // g = gelu(x @ Wf1^T + bf1) -> gbuf bf16; grid 128*8 = 1024
        gemm256_kernel<1, 1, 0, 0><<<dim3(1024), blk512, 0, stream>>>(
            xb + off, wf1b, bf1, nullptr, gbuf, nullptr, nullptr,
            32768, 2048, 512);
        // h2 = x + g @ Wf2^T + bf2 -> h2b bf16; grid 128*2 = 256
        gemm256_kernel<0, 1, 2, 0><<<dim3(256), blk512, 0, stream>>>(
            gbuf, wf2b, bf2_, xb + off, h2b + off, nullptr, nullptr,
            32768, 512, 2048);
    }
    // out = LN2(h2) -> d_out f32
    ln_kernel<1, 0><<<dim3(32768), blk, 0, stream>>>(h2b, g2, b2, out);
}